// Round 1
// baseline (59.140 us; speedup 1.0000x reference)
//
#include <hip/hip_runtime.h>

// GlobalConvolutionalLayer: out[n,c,m] = 0.5*xi_eff[c]*dx * sum_l d[n,l]*exp(-|x_l-x_m|*xi_eff[c])
// Separable exponential kernel on a sorted uniform grid -> prefix/suffix scans, O(G) per (n,c).
// xi_eff = 1/sigmoid(xi) = 1 + exp(-xi) in (1.37, 2]; exp(x*xi_eff) <= e^2, no overflow.

#define GG 4096
#define CC 8
#define NN 4
#define BLOCK 256
#define CHUNK (GG / BLOCK)  // 16 elements per thread

__global__ __launch_bounds__(BLOCK) void gconv_scan(const float* __restrict__ density,
                                                    const float* __restrict__ xi,
                                                    const float* __restrict__ grid,
                                                    float* __restrict__ out) {
    const int bid  = blockIdx.x;          // n*C + c  (matches output layout (N,C,G))
    const int c    = bid & (CC - 1);
    const int n    = bid >> 3;
    const int tid  = threadIdx.x;
    const int base = tid * CHUNK;

    const float k  = 1.0f + expf(-xi[c]); // xi_eff = 1/sigmoid(xi)
    const float dx = grid[1] - grid[0];   // uniform spacing = 1/G

    const float4* dv4 = reinterpret_cast<const float4*>(density + n * GG + base);
    const float4* gv4 = reinterpret_cast<const float4*>(grid + base);

    float ea[CHUNK];  // exp(+x*k)
    float eb[CHUNK];  // exp(-x*k)
    float pa[CHUNK];  // intra-chunk inclusive prefix of a[l] = d[l]*exp(+x_l*k)
    float sb[CHUNK];  // first b[l] = d[l]*exp(-x_l*k), then intra-chunk exclusive suffix

    float runA = 0.0f;
#pragma unroll
    for (int q = 0; q < CHUNK / 4; ++q) {
        float4 d4 = dv4[q];
        float4 g4 = gv4[q];
        float xs[4] = {g4.x, g4.y, g4.z, g4.w};
        float ds[4] = {d4.x, d4.y, d4.z, d4.w};
#pragma unroll
        for (int j = 0; j < 4; ++j) {
            const int i = q * 4 + j;
            const float e  = expf(xs[j] * k);
            const float ei = expf(-xs[j] * k);
            ea[i] = e;
            eb[i] = ei;
            runA += ds[j] * e;
            pa[i] = runA;
            sb[i] = ds[j] * ei;   // stash b value
        }
    }
    // intra-chunk exclusive suffix of b
    float runB = 0.0f;
#pragma unroll
    for (int i = CHUNK - 1; i >= 0; --i) {
        const float bv = sb[i];
        sb[i] = runB;
        runB += bv;
    }

    // wave-level (64-lane) inclusive scans of thread totals runA / runB
    float sA = runA, sB = runB;
#pragma unroll
    for (int off = 1; off < 64; off <<= 1) {
        const float tA = __shfl_up(sA, off, 64);
        const float tB = __shfl_up(sB, off, 64);
        if ((tid & 63) >= off) { sA += tA; sB += tB; }
    }

    __shared__ float wA[BLOCK / 64];
    __shared__ float wB[BLOCK / 64];
    const int wave = tid >> 6;
    if ((tid & 63) == 63) { wA[wave] = sA; wB[wave] = sB; }
    __syncthreads();

    float preA = 0.0f, preB = 0.0f, totB = 0.0f;
#pragma unroll
    for (int w = 0; w < BLOCK / 64; ++w) {
        const float ta = wA[w];
        const float tb = wB[w];
        if (w < wave) { preA += ta; preB += tb; }
        totB += tb;
    }
    const float offA = preA + (sA - runA);  // exclusive prefix across all threads
    const float offB = totB - (preB + sB);  // exclusive suffix across all threads

    const float scale = 0.5f * k * dx;
    float4* o4 = reinterpret_cast<float4*>(out + bid * GG + base);
#pragma unroll
    for (int q = 0; q < CHUNK / 4; ++q) {
        float4 r;
        float* rp = &r.x;
#pragma unroll
        for (int j = 0; j < 4; ++j) {
            const int i = q * 4 + j;
            const float A = offA + pa[i];     // sum_{l<=m} d[l]*e^{+x_l k}
            const float B = offB + sb[i];     // sum_{l> m} d[l]*e^{-x_l k}
            rp[j] = scale * (eb[i] * A + ea[i] * B);
        }
        o4[q] = r;
    }
}

extern "C" void kernel_launch(void* const* d_in, const int* in_sizes, int n_in,
                              void* d_out, int out_size, void* d_ws, size_t ws_size,
                              hipStream_t stream) {
    const float* density = (const float*)d_in[0];  // (N,1,G) fp32
    const float* xi      = (const float*)d_in[1];  // (C,)    fp32
    const float* grid    = (const float*)d_in[2];  // (G,)    fp32
    float* out           = (float*)d_out;          // (N,C,G) fp32

    gconv_scan<<<NN * CC, BLOCK, 0, stream>>>(density, xi, grid, out);
}